// Round 1
// baseline (2795.482 us; speedup 1.0000x reference)
//
// TransformerDecoderBlock on MI355X (gfx950) — round 0: correctness-first full bf16-MFMA pipeline.
// Pipeline: causal self-attn -> @Wo1^T + x -> LN(S,D) -> cross-attn(enc,enc,v=x) -> @Wo2^T + x
//           -> LN -> FFN(relu(xW1^T+b1)W2^T+b2) + x -> LN (ln2 params reused).
// Requires ws_size >= ~101 MB (guarded).
#include <hip/hip_runtime.h>
#include <cstdint>
#include <cstddef>

#define NB 4
#define NS 4096
#define ND 512
#define NF 2048

typedef __bf16 bf16;
typedef __attribute__((ext_vector_type(8))) __bf16 bf16x8;
typedef __attribute__((ext_vector_type(4))) float f32x4;

#define MFMA16(a, b, c) __builtin_amdgcn_mfma_f32_16x16x32_bf16((a), (b), (c), 0, 0, 0)

// Async global->LDS, 16B per lane. LDS dest must be wave-uniform base; lane i lands at base+16*i.
__device__ __forceinline__ void async_copy16(void* lds, const void* g) {
  __builtin_amdgcn_global_load_lds(
      (__attribute__((address_space(1))) unsigned int*)(uintptr_t)g,
      (__attribute__((address_space(3))) unsigned int*)(unsigned)(uintptr_t)lds,
      16, 0, 0);
}

// ---------------- dtype detect ----------------
// If inputs are f32 viewed as bf16, half the 16-bit words have garbage exponents.
__global__ void k_detect(const unsigned short* __restrict__ x, unsigned* __restrict__ flag) {
  __shared__ int cnt;
  if (threadIdx.x == 0) cnt = 0;
  __syncthreads();
  int bad = 0;
  for (int i = threadIdx.x; i < 2048; i += 256) {
    unsigned e = (x[i] >> 7) & 0xFF;
    if (e < 100 || e > 140) bad++;
  }
  atomicAdd(&cnt, bad);
  __syncthreads();
  if (threadIdx.x == 0) *flag = (cnt > 200) ? 1u : 0u;  // 1 => inputs are f32
}

// ---------------- input normalization ----------------
__global__ void k_norm_bf16(const void* __restrict__ src, bf16* __restrict__ dst,
                            const unsigned* __restrict__ flag, int n) {
  int i = (blockIdx.x * 256 + threadIdx.x) * 8;
  if (i >= n) return;
  if (*flag) {
    const float* s = (const float*)src;
    float4 a = *(const float4*)(s + i);
    float4 c = *(const float4*)(s + i + 4);
    bf16x8 v;
    v[0] = (bf16)a.x; v[1] = (bf16)a.y; v[2] = (bf16)a.z; v[3] = (bf16)a.w;
    v[4] = (bf16)c.x; v[5] = (bf16)c.y; v[6] = (bf16)c.z; v[7] = (bf16)c.w;
    *(bf16x8*)(dst + i) = v;
  } else {
    *(uint4*)(dst + i) = *(const uint4*)((const bf16*)src + i);
  }
}

__global__ void k_norm_f32(const void* __restrict__ src, float* __restrict__ dst,
                           const unsigned* __restrict__ flag, int n) {
  int i = blockIdx.x * 256 + threadIdx.x;
  if (i >= n) return;
  dst[i] = (*flag) ? ((const float*)src)[i] : (float)((const bf16*)src)[i];
}

// ---------------- transpose [B][S][D] -> [B][D][S] (bf16) ----------------
__global__ void k_transpose(const bf16* __restrict__ in, bf16* __restrict__ out) {
  __shared__ bf16 t[64][72];
  const int b = blockIdx.z, s0 = blockIdx.x * 64, d0 = blockIdx.y * 64;
  const int tid = threadIdx.x;
#pragma unroll
  for (int it = 0; it < 2; ++it) {
    int slot = it * 256 + tid;
    int r = slot >> 3, c = (slot & 7) * 8;
    *(bf16x8*)&t[r][c] = *(const bf16x8*)&in[((size_t)b * NS + s0 + r) * ND + d0 + c];
  }
  __syncthreads();
#pragma unroll
  for (int it = 0; it < 2; ++it) {
    int slot = it * 256 + tid;
    int r = slot >> 3, c = (slot & 7) * 8;  // r = local dim, c = local seq base
    bf16x8 v;
#pragma unroll
    for (int k = 0; k < 8; ++k) v[k] = t[c + k][r];
    *(bf16x8*)&out[((size_t)b * ND + d0 + r) * NS + s0 + c] = v;
  }
}

// ---------------- flash attention ----------------
// Q,K: [B][S][D] bf16. Vt: [B][D][S] bf16 (pre-transposed). O: [B][S][D] bf16.
// Block: 256 thr (4 waves), BQ=32 queries, K-tile 64 keys, D chunked by 128.
// mfma 16x16x32_bf16: A[m=lane&15][k=quad*8+j]; B[n=lane&15][k=quad*8+j]; C row=quad*4+reg, col=lane&15.
template <bool CAUSAL>
__global__ __launch_bounds__(256) void k_attn(const bf16* __restrict__ Q,
                                              const bf16* __restrict__ Km,
                                              const bf16* __restrict__ Vt,
                                              bf16* __restrict__ O) {
  __shared__ bf16 Qs[32 * 128];   // Q chunk [32 q][128 d]
  __shared__ bf16 Ks[64 * 128];   // K chunk [64 k][128 d]
  __shared__ bf16 Vs[128 * 64];   // V chunk [128 d][64 k]
  __shared__ bf16 Ps[32 * 72];    // P [32 q][64 k], padded stride 72
  __shared__ float Mred[4][32];
  __shared__ float Sred[4][32];
  __shared__ float Mrow[32];
  __shared__ float Lrow[32];

  const int tid = threadIdx.x;
  const int w = tid >> 6, lane = tid & 63, quad = lane >> 4, l15 = lane & 15;
  const int b = blockIdx.y;
  const int q0 = blockIdx.x * 32;

  const bf16* Qg = Q + ((size_t)b * NS + q0) * ND;
  const bf16* Kg0 = Km + (size_t)b * NS * ND;
  const bf16* Vg = Vt + (size_t)b * ND * NS;

  if (tid < 32) { Mrow[tid] = -1e30f; Lrow[tid] = 0.f; }

  f32x4 o[16];
#pragma unroll
  for (int i = 0; i < 16; ++i) o[i] = (f32x4){0.f, 0.f, 0.f, 0.f};

  const float scale = 0.044194173824159216f;  // 1/sqrt(512)
  const int nkt = CAUSAL ? (q0 + 31) / 64 + 1 : NS / 64;

  for (int kt = 0; kt < nkt; ++kt) {
    const int k0 = kt * 64;
    const bf16* Kg = Kg0 + (size_t)k0 * ND;
    f32x4 sacc[2] = {(f32x4){0.f, 0.f, 0.f, 0.f}, (f32x4){0.f, 0.f, 0.f, 0.f}};

    // ---- pass 1: scores = Q K^T over 4 dim-chunks ----
    for (int dc = 0; dc < 4; ++dc) {
      __syncthreads();
#pragma unroll
      for (int i = 0; i < 2; ++i)  // Q chunk: 8 instrs of 4 rows
        async_copy16(&Qs[(w * 2 + i) * 512],
                     Qg + (size_t)((w * 2 + i) * 4 + quad) * ND + dc * 128 + l15 * 8);
#pragma unroll
      for (int i = 0; i < 4; ++i)  // K chunk: 16 instrs of 4 rows
        async_copy16(&Ks[(w * 4 + i) * 512],
                     Kg + (size_t)((w * 4 + i) * 4 + quad) * ND + dc * 128 + l15 * 8);
      __syncthreads();
#pragma unroll
      for (int s = 0; s < 4; ++s) {
        bf16x8 bb = *(const bf16x8*)&Ks[(w * 16 + l15) * 128 + s * 32 + quad * 8];
#pragma unroll
        for (int t = 0; t < 2; ++t) {
          bf16x8 a = *(const bf16x8*)&Qs[(t * 16 + l15) * 128 + s * 32 + quad * 8];
          sacc[t] = MFMA16(a, bb, sacc[t]);
        }
      }
    }

    // ---- scale + causal mask ----
    float sv[2][4];
#pragma unroll
    for (int t = 0; t < 2; ++t)
#pragma unroll
      for (int r = 0; r < 4; ++r) {
        float s = sacc[t][r] * scale;
        if (CAUSAL && (k0 + 63 > q0)) {
          int key = k0 + w * 16 + l15;
          int qq = q0 + t * 16 + quad * 4 + r;
          if (key > qq) s = -1e30f;
        }
        sv[t][r] = s;
      }

    // ---- per-wave row max (over this wave's 16 key-cols) ----
#pragma unroll
    for (int t = 0; t < 2; ++t)
#pragma unroll
      for (int r = 0; r < 4; ++r) {
        float v = sv[t][r];
        v = fmaxf(v, __shfl_xor(v, 1));
        v = fmaxf(v, __shfl_xor(v, 2));
        v = fmaxf(v, __shfl_xor(v, 4));
        v = fmaxf(v, __shfl_xor(v, 8));
        if (l15 == 0) Mred[w][t * 16 + quad * 4 + r] = v;
      }
    __syncthreads();

    // ---- online softmax update ----
    float al[2][4], mnv[2][4];
#pragma unroll
    for (int t = 0; t < 2; ++t)
#pragma unroll
      for (int r = 0; r < 4; ++r) {
        int row = t * 16 + quad * 4 + r;
        float tm = fmaxf(fmaxf(Mred[0][row], Mred[1][row]), fmaxf(Mred[2][row], Mred[3][row]));
        float mo = Mrow[row];
        float mn = fmaxf(mo, tm);
        float alpha = __expf(mo - mn);
        float p = __expf(sv[t][r] - mn);
        al[t][r] = alpha;
        mnv[t][r] = mn;
        Ps[row * 72 + w * 16 + l15] = (bf16)p;
        float ps = p;
        ps += __shfl_xor(ps, 1);
        ps += __shfl_xor(ps, 2);
        ps += __shfl_xor(ps, 4);
        ps += __shfl_xor(ps, 8);
        if (l15 == 0) Sred[w][row] = ps;
      }
    __syncthreads();
    if (w == 0 && l15 == 0) {
#pragma unroll
      for (int t = 0; t < 2; ++t)
#pragma unroll
        for (int r = 0; r < 4; ++r) {
          int row = t * 16 + quad * 4 + r;
          Mrow[row] = mnv[t][r];
          Lrow[row] = al[t][r] * Lrow[row] + Sred[0][row] + Sred[1][row] + Sred[2][row] + Sred[3][row];
        }
    }
    // rescale O accumulators
#pragma unroll
    for (int dc = 0; dc < 4; ++dc)
#pragma unroll
      for (int ct = 0; ct < 2; ++ct)
#pragma unroll
        for (int t = 0; t < 2; ++t) {
          f32x4& oo = o[dc * 4 + ct * 2 + t];
#pragma unroll
          for (int r = 0; r < 4; ++r) oo[r] *= al[t][r];
        }

    // ---- pass 2: O += P V over 4 dim-chunks; wave w owns 32 cols per chunk ----
    for (int dc = 0; dc < 4; ++dc) {
      __syncthreads();
#pragma unroll
      for (int i = 0; i < 4; ++i)  // V chunk: 16 instrs of 8 rows (dims)
        async_copy16(&Vs[(w * 4 + i) * 512],
                     Vg + (size_t)(dc * 128 + (w * 4 + i) * 8 + (lane >> 3)) * NS + k0 + (lane & 7) * 8);
      __syncthreads();
#pragma unroll
      for (int s = 0; s < 2; ++s) {
        bf16x8 a0 = *(const bf16x8*)&Ps[(0 * 16 + l15) * 72 + s * 32 + quad * 8];
        bf16x8 a1 = *(const bf16x8*)&Ps[(1 * 16 + l15) * 72 + s * 32 + quad * 8];
#pragma unroll
        for (int ct = 0; ct < 2; ++ct) {
          bf16x8 bb = *(const bf16x8*)&Vs[(w * 32 + ct * 16 + l15) * 64 + s * 32 + quad * 8];
          o[dc * 4 + ct * 2 + 0] = MFMA16(a0, bb, o[dc * 4 + ct * 2 + 0]);
          o[dc * 4 + ct * 2 + 1] = MFMA16(a1, bb, o[dc * 4 + ct * 2 + 1]);
        }
      }
    }
  }

  __syncthreads();
  float rl[2][4];
#pragma unroll
  for (int t = 0; t < 2; ++t)
#pragma unroll
    for (int r = 0; r < 4; ++r) rl[t][r] = 1.f / Lrow[t * 16 + quad * 4 + r];

  bf16* Og = O + ((size_t)b * NS + q0) * ND;
#pragma unroll
  for (int dc = 0; dc < 4; ++dc)
#pragma unroll
    for (int ct = 0; ct < 2; ++ct)
#pragma unroll
      for (int t = 0; t < 2; ++t)
#pragma unroll
        for (int r = 0; r < 4; ++r) {
          int row = t * 16 + quad * 4 + r;
          int col = dc * 128 + w * 32 + ct * 16 + l15;
          Og[(size_t)row * ND + col] = (bf16)(o[dc * 4 + ct * 2 + t][r] * rl[t][r]);
        }
}

// ---------------- NT GEMM: Out[M,N] = A[M,K] * W[N,K]^T (+bias)(+relu)(+res)(+LN stats) ----------------
template <int RES_MODE, bool HAS_BIAS, bool RELU, bool STATS>
__global__ __launch_bounds__(256) void k_gemm(const bf16* __restrict__ A, const bf16* __restrict__ W,
                                              const bf16* __restrict__ resid,
                                              const float* __restrict__ bias, bf16* __restrict__ Out,
                                              float* __restrict__ stats, int M, int N, int K,
                                              int rowOfs) {
  __shared__ bf16 As[128 * 64];
  __shared__ bf16 Ws[128 * 64];
  const int tid = threadIdx.x;
  const int w = tid >> 6, lane = tid & 63, quad = lane >> 4, l15 = lane & 15;
  const int m0 = blockIdx.x * 128, n0 = blockIdx.y * 128;
  const int wr = (w >> 1) * 64, wc = (w & 1) * 64;
  const int arow = lane >> 3, acol = (lane & 7) * 8;

  f32x4 acc[16];
#pragma unroll
  for (int i = 0; i < 16; ++i) acc[i] = (f32x4){0.f, 0.f, 0.f, 0.f};

  for (int k0 = 0; k0 < K; k0 += 64) {
    __syncthreads();
#pragma unroll
    for (int i = 0; i < 4; ++i) {
      const int rbase = (w * 4 + i) * 8 + arow;
      async_copy16(&As[(w * 4 + i) * 512], A + (size_t)(m0 + rbase) * K + k0 + acol);
      async_copy16(&Ws[(w * 4 + i) * 512], W + (size_t)(n0 + rbase) * K + k0 + acol);
    }
    __syncthreads();
#pragma unroll
    for (int s = 0; s < 2; ++s) {
      bf16x8 af[4], bw[4];
#pragma unroll
      for (int i = 0; i < 4; ++i) af[i] = *(const bf16x8*)&As[(wr + i * 16 + l15) * 64 + s * 32 + quad * 8];
#pragma unroll
      for (int j = 0; j < 4; ++j) bw[j] = *(const bf16x8*)&Ws[(wc + j * 16 + l15) * 64 + s * 32 + quad * 8];
#pragma unroll
      for (int i = 0; i < 4; ++i)
#pragma unroll
        for (int j = 0; j < 4; ++j) acc[i * 4 + j] = MFMA16(af[i], bw[j], acc[i * 4 + j]);
    }
  }

  float lsum = 0.f, lsq = 0.f;
#pragma unroll
  for (int i = 0; i < 4; ++i)
#pragma unroll
    for (int j = 0; j < 4; ++j)
#pragma unroll
      for (int r = 0; r < 4; ++r) {
        int row = m0 + wr + i * 16 + quad * 4 + r;
        int col = n0 + wc + j * 16 + l15;
        float v = acc[i * 4 + j][r];
        if (HAS_BIAS) v += bias[col];
        if (RELU) v = fmaxf(v, 0.f);
        if (RES_MODE == 2) v += (float)resid[(size_t)row * N + col];
        Out[(size_t)row * N + col] = (bf16)v;
        if (STATS) { lsum += v; lsq += v * v; }
      }

  if (STATS) {
    __syncthreads();
    float* red = (float*)As;
    red[tid] = lsum;
    red[256 + tid] = lsq;
    __syncthreads();
    for (int off = 128; off > 0; off >>= 1) {
      if (tid < off) { red[tid] += red[tid + off]; red[256 + tid] += red[256 + tid + off]; }
      __syncthreads();
    }
    if (tid == 0) {
      int bidx = (rowOfs + m0) >> 12;  // 4096 rows per batch
      atomicAdd(&stats[bidx * 2], red[0]);
      atomicAdd(&stats[bidx * 2 + 1], red[256]);
    }
  }
}

// ---------------- LayerNorm apply over (S,D) jointly per batch ----------------
template <bool FINAL>
__global__ void k_ln(const bf16* __restrict__ T, const float* __restrict__ stats,
                     const void* __restrict__ gp, const void* __restrict__ bp,
                     void* __restrict__ outp, const unsigned* __restrict__ flag) {
  const float invN = 1.f / 2097152.f;
  size_t i = ((size_t)(blockIdx.x * 256 + threadIdx.x)) * 8;
  int b = (int)(i >> 21);
  int sd = (int)(i & 2097151);
  float mu = stats[b * 2] * invN;
  float var = stats[b * 2 + 1] * invN - mu * mu;
  float rs = rsqrtf(var + 1e-5f);
  bool f32m = (*flag != 0);
  bf16x8 tv = *(const bf16x8*)(T + i);
  float gv[8], bv[8];
  if (f32m) {
    float4 a = *(const float4*)((const float*)gp + sd), c = *(const float4*)((const float*)gp + sd + 4);
    gv[0] = a.x; gv[1] = a.y; gv[2] = a.z; gv[3] = a.w; gv[4] = c.x; gv[5] = c.y; gv[6] = c.z; gv[7] = c.w;
    float4 e = *(const float4*)((const float*)bp + sd), f = *(const float4*)((const float*)bp + sd + 4);
    bv[0] = e.x; bv[1] = e.y; bv[2] = e.z; bv[3] = e.w; bv[4] = f.x; bv[5] = f.y; bv[6] = f.z; bv[7] = f.w;
  } else {
    bf16x8 g8 = *(const bf16x8*)((const bf16*)gp + sd);
    bf16x8 b8 = *(const bf16x8*)((const bf16*)bp + sd);
#pragma unroll
    for (int k = 0; k < 8; ++k) { gv[k] = (float)g8[k]; bv[k] = (float)b8[k]; }
  }
  float ov[8];
#pragma unroll
  for (int k = 0; k < 8; ++k) ov[k] = ((float)tv[k] - mu) * rs * gv[k] + bv[k];
  if (FINAL && f32m) {
    float4 o0 = {ov[0], ov[1], ov[2], ov[3]}, o1 = {ov[4], ov[5], ov[6], ov[7]};
    *(float4*)((float*)outp + i) = o0;
    *(float4*)((float*)outp + i + 4) = o1;
  } else {
    bf16x8 o8;
#pragma unroll
    for (int k = 0; k < 8; ++k) o8[k] = (bf16)ov[k];
    *(bf16x8*)((bf16*)outp + i) = o8;
  }
}

// ---------------- launch ----------------
extern "C" void kernel_launch(void* const* d_in, const int* in_sizes, int n_in, void* d_out,
                              int out_size, void* d_ws, size_t ws_size, hipStream_t stream) {
  (void)in_sizes; (void)n_in; (void)out_size;
  const void* x_raw = d_in[0];
  const void* enc_raw = d_in[1];
  const void* Wo1_raw = d_in[2];
  const void* Wo2_raw = d_in[3];
  const void* g1_raw = d_in[4];
  const void* bb1_raw = d_in[5];
  const void* g2_raw = d_in[6];
  const void* bb2_raw = d_in[7];
  const void* W1_raw = d_in[8];
  const void* bias1_raw = d_in[9];
  const void* W2_raw = d_in[10];
  const void* bias2_raw = d_in[11];

  char* w = (char*)d_ws;
  unsigned* flag = (unsigned*)(w + 0);
  float* stats = (float*)(w + 16);  // 3 stages x [B][2]
  float* b1f = (float*)(w + 1024);
  float* b2f = (float*)(w + 1024 + 8192);
  size_t off = 16384;
  const size_t nBSD = (size_t)NB * NS * ND;
  bf16* Wo1b = (bf16*)(w + off); off += (size_t)ND * ND * 2;
  bf16* Wo2b = (bf16*)(w + off); off += (size_t)ND * ND * 2;
  bf16* W1b = (bf16*)(w + off); off += (size_t)NF * ND * 2;
  bf16* W2b = (bf16*)(w + off); off += (size_t)ND * NF * 2;
  bf16* xb = (bf16*)(w + off); off += nBSD * 2;   // x bf16, later reused for enc
  bf16* Ab = (bf16*)(w + off); off += nBSD * 2;   // attention outputs
  bf16* Tb = (bf16*)(w + off); off += nBSD * 2;   // transposed-V scratch / pre-LN tensor
  bf16* X1b = (bf16*)(w + off); off += nBSD * 2;  // X1, later X2
  bf16* Hb = (bf16*)(w + off); off += (size_t)8192 * NF * 2;  // FFN hidden (half of M)
  if (ws_size < off) return;  // ~101 MB required; leaves d_out zeroed -> visible as stub-like failure

  hipMemsetAsync(stats, 0, 24 * sizeof(float), stream);
  k_detect<<<1, 256, 0, stream>>>((const unsigned short*)x_raw, flag);

  k_norm_bf16<<<(int)(nBSD / 2048), 256, 0, stream>>>(x_raw, xb, flag, (int)nBSD);
  k_norm_bf16<<<(ND * ND) / 2048, 256, 0, stream>>>(Wo1_raw, Wo1b, flag, ND * ND);
  k_norm_bf16<<<(ND * ND) / 2048, 256, 0, stream>>>(Wo2_raw, Wo2b, flag, ND * ND);
  k_norm_bf16<<<(NF * ND) / 2048, 256, 0, stream>>>(W1_raw, W1b, flag, NF * ND);
  k_norm_bf16<<<(NF * ND) / 2048, 256, 0, stream>>>(W2_raw, W2b, flag, ND * NF);
  k_norm_f32<<<8, 256, 0, stream>>>(bias1_raw, b1f, flag, NF);
  k_norm_f32<<<2, 256, 0, stream>>>(bias2_raw, b2f, flag, ND);

  // 1) causal self-attention + Wo1 + residual(x) + LN1
  k_transpose<<<dim3(NS / 64, ND / 64, NB), 256, 0, stream>>>(xb, Tb);        // x^T as V
  k_attn<true><<<dim3(NS / 32, NB), 256, 0, stream>>>(xb, xb, Tb, Ab);
  k_gemm<2, false, false, true><<<dim3(128, 4), 256, 0, stream>>>(Ab, Wo1b, xb, nullptr, Tb,
                                                                  stats + 0, NB * NS, ND, ND, 0);
  k_norm_bf16<<<(int)(nBSD / 2048), 256, 0, stream>>>(enc_raw, xb, flag, (int)nBSD);  // xb := enc
  k_ln<false><<<(int)(nBSD / 2048), 256, 0, stream>>>(Tb, stats + 0, g1_raw, bb1_raw, X1b, flag);

  // 2) cross attention (q=k=enc, v=X1) + Wo2 + residual(X1) + LN2
  k_transpose<<<dim3(NS / 64, ND / 64, NB), 256, 0, stream>>>(X1b, Tb);       // X1^T as V
  k_attn<false><<<dim3(NS / 32, NB), 256, 0, stream>>>(xb, xb, Tb, Ab);
  k_gemm<2, false, false, true><<<dim3(128, 4), 256, 0, stream>>>(Ab, Wo2b, X1b, nullptr, Tb,
                                                                  stats + 8, NB * NS, ND, ND, 0);
  k_ln<false><<<(int)(nBSD / 2048), 256, 0, stream>>>(Tb, stats + 8, g2_raw, bb2_raw, X1b, flag);
  // X1b now holds X2

  // 3) FFN + residual(X2) + LN (ln2 params), in two 8192-row chunks
  for (int c = 0; c < 2; ++c) {
    size_t ro = (size_t)c * 8192;
    k_gemm<0, true, true, false><<<dim3(64, 16), 256, 0, stream>>>(X1b + ro * ND, W1b, nullptr, b1f,
                                                                   Hb, nullptr, 8192, NF, ND, 0);
    k_gemm<2, true, false, true><<<dim3(64, 4), 256, 0, stream>>>(Hb, W2b, X1b + ro * ND, b2f,
                                                                  Tb + ro * ND, stats + 16, 8192,
                                                                  ND, NF, (int)ro);
  }
  k_ln<true><<<(int)(nBSD / 2048), 256, 0, stream>>>(Tb, stats + 16, g2_raw, bb2_raw, d_out, flag);
}

// Round 2
// 1101.613 us; speedup vs baseline: 2.5376x; 2.5376x over previous
//
// TransformerDecoderBlock on MI355X (gfx950) — round 2: flash-attn rewrite.
// Attention: BQ=64 (4 waves x 16 q-rows), BK=32 full-D tiles, Q in registers,
// S^T = K*Q^T (wave-local softmax), in-register P^T->B via ds_bpermute,
// O^T accumulators, 2 barriers/K-tile, XOR-swizzled K staging.
// GEMM/LN pipeline unchanged from round 0. Requires ws_size >= ~101 MB.
#include <hip/hip_runtime.h>
#include <cstdint>
#include <cstddef>

#define NB 4
#define NS 4096
#define ND 512
#define NF 2048

typedef __bf16 bf16;
typedef __attribute__((ext_vector_type(8))) __bf16 bf16x8;
typedef __attribute__((ext_vector_type(4))) __bf16 bf16x4;
typedef __attribute__((ext_vector_type(4))) float f32x4;

#define MFMA16(a, b, c) __builtin_amdgcn_mfma_f32_16x16x32_bf16((a), (b), (c), 0, 0, 0)

// Async global->LDS, 16B per lane. LDS dest is wave-uniform base; lane i lands at base+16*i.
__device__ __forceinline__ void async_copy16(void* lds, const void* g) {
  __builtin_amdgcn_global_load_lds(
      (__attribute__((address_space(1))) unsigned int*)(uintptr_t)g,
      (__attribute__((address_space(3))) unsigned int*)(unsigned)(uintptr_t)lds,
      16, 0, 0);
}

// ---------------- dtype detect ----------------
__global__ void k_detect(const unsigned short* __restrict__ x, unsigned* __restrict__ flag) {
  __shared__ int cnt;
  if (threadIdx.x == 0) cnt = 0;
  __syncthreads();
  int bad = 0;
  for (int i = threadIdx.x; i < 2048; i += 256) {
    unsigned e = (x[i] >> 7) & 0xFF;
    if (e < 100 || e > 140) bad++;
  }
  atomicAdd(&cnt, bad);
  __syncthreads();
  if (threadIdx.x == 0) *flag = (cnt > 200) ? 1u : 0u;  // 1 => inputs are f32
}

// ---------------- input normalization ----------------
__global__ void k_norm_bf16(const void* __restrict__ src, bf16* __restrict__ dst,
                            const unsigned* __restrict__ flag, int n) {
  int i = (blockIdx.x * 256 + threadIdx.x) * 8;
  if (i >= n) return;
  if (*flag) {
    const float* s = (const float*)src;
    float4 a = *(const float4*)(s + i);
    float4 c = *(const float4*)(s + i + 4);
    bf16x8 v;
    v[0] = (bf16)a.x; v[1] = (bf16)a.y; v[2] = (bf16)a.z; v[3] = (bf16)a.w;
    v[4] = (bf16)c.x; v[5] = (bf16)c.y; v[6] = (bf16)c.z; v[7] = (bf16)c.w;
    *(bf16x8*)(dst + i) = v;
  } else {
    *(uint4*)(dst + i) = *(const uint4*)((const bf16*)src + i);
  }
}

__global__ void k_norm_f32(const void* __restrict__ src, float* __restrict__ dst,
                           const unsigned* __restrict__ flag, int n) {
  int i = blockIdx.x * 256 + threadIdx.x;
  if (i >= n) return;
  dst[i] = (*flag) ? ((const float*)src)[i] : (float)((const bf16*)src)[i];
}

// ---------------- transpose [B][S][D] -> [B][D][S] (bf16) ----------------
__global__ void k_transpose(const bf16* __restrict__ in, bf16* __restrict__ out) {
  __shared__ bf16 t[64][72];
  const int b = blockIdx.z, s0 = blockIdx.x * 64, d0 = blockIdx.y * 64;
  const int tid = threadIdx.x;
#pragma unroll
  for (int it = 0; it < 2; ++it) {
    int slot = it * 256 + tid;
    int r = slot >> 3, c = (slot & 7) * 8;
    *(bf16x8*)&t[r][c] = *(const bf16x8*)&in[((size_t)b * NS + s0 + r) * ND + d0 + c];
  }
  __syncthreads();
#pragma unroll
  for (int it = 0; it < 2; ++it) {
    int slot = it * 256 + tid;
    int r = slot >> 3, c = (slot & 7) * 8;  // r = local dim, c = local seq base
    bf16x8 v;
#pragma unroll
    for (int k = 0; k < 8; ++k) v[k] = t[c + k][r];
    *(bf16x8*)&out[((size_t)b * ND + d0 + r) * NS + s0 + c] = v;
  }
}

// ---------------- flash attention (round-2 design) ----------------
// Q,K: [B][S][D] bf16. Vt: [B][D][S] bf16 (pre-transposed). O: [B][S][D] bf16.
// 256 thr (4 waves); wave w owns q-rows [q0+w*16, +16). BK=32 keys/tile.
// S^T = K*Q^T: A=K-frag (m=key), B=Q-frag (n=q, registers). C: row=key(quad*4+r), col=q(l15).
// PV as O^T = V^T * P: A=V^T-frag (m=d), B=P^T-frag (n=q, built via ds_bpermute).
template <bool CAUSAL>
__global__ __launch_bounds__(256, 1) void k_attn2(const bf16* __restrict__ Q,
                                                  const bf16* __restrict__ Km,
                                                  const bf16* __restrict__ Vt,
                                                  bf16* __restrict__ O) {
  __shared__ bf16 lds_[32768];  // 64 KB: Ks = [0,16384) elems (32 rows x 512), Vs = [16384,32768) (512 rows x 32)
  bf16* Ks = lds_;
  bf16* Vs = lds_ + 16384;

  const int tid = threadIdx.x;
  const int w = tid >> 6, lane = tid & 63, quad = lane >> 4, l15 = lane & 15;
  const int b = blockIdx.y;
  const int q0 = blockIdx.x * 64;

  const bf16* Kg = Km + (size_t)b * NS * ND;
  const bf16* Vg = Vt + (size_t)b * ND * NS;

  // ---- Q fragments in registers, pre-scaled by 1/sqrt(D) ----
  const bf16* Qg = Q + ((size_t)b * NS + q0 + w * 16 + l15) * ND;
  bf16x8 qf[16];
#pragma unroll
  for (int s = 0; s < 16; ++s) qf[s] = *(const bf16x8*)&Qg[s * 32 + quad * 8];
#pragma unroll
  for (int s = 0; s < 16; ++s)
#pragma unroll
    for (int j = 0; j < 8; ++j) qf[s][j] = (bf16)((float)qf[s][j] * 0.044194173824159216f);

  f32x4 o[32];  // O^T: o[dt] -> (d = dt*16 + quad*4 + r, q = l15)
#pragma unroll
  for (int i = 0; i < 32; ++i) o[i] = (f32x4){0.f, 0.f, 0.f, 0.f};

  float m = -1e30f, l = 0.f;  // per-lane, q = l15 (replicated across quads)

  const int nkt = CAUSAL ? (q0 / 32 + 2) : (NS / 32);
  const int laneA4 = ((((quad * 2) & 3) * 16) + l15) * 4;
  const int laneB4 = ((((quad * 2 + 1) & 3) * 16) + l15) * 4;

  for (int kt = 0; kt < nkt; ++kt) {
    const int k0 = kt * 32;
    __syncthreads();  // previous tile's LDS reads complete

    // ---- stage K tile [32][512] with per-row XOR-swizzle on 16B chunks ----
#pragma unroll
    for (int i = 0; i < 8; ++i) {
      const int r = w * 8 + i;
      const int g = (lane & ~7) | ((lane ^ r) & 7);
      async_copy16(&Ks[r * 512], Kg + (size_t)(k0 + r) * ND + g * 8);
    }
    // ---- stage V^T tile [512][32] ----
#pragma unroll
    for (int i = 0; i < 8; ++i) {
      const int d0 = (w * 8 + i) * 16;
      async_copy16(&Vs[d0 * 32], Vg + (size_t)(d0 + (lane >> 2)) * NS + k0 + (lane & 3) * 8);
    }
    __syncthreads();  // staging drained

    // ---- S^T = K * Q^T ----
    f32x4 sa0 = (f32x4){0.f, 0.f, 0.f, 0.f};
    f32x4 sa1 = (f32x4){0.f, 0.f, 0.f, 0.f};
#pragma unroll
    for (int s = 0; s < 16; ++s) {
      const int lc = s * 4 + quad;
      const int swz = ((lc & ~7) | ((lc ^ l15) & 7)) * 8;
      bf16x8 a0 = *(const bf16x8*)&Ks[l15 * 512 + swz];
      bf16x8 a1 = *(const bf16x8*)&Ks[(16 + l15) * 512 + swz];
      sa0 = MFMA16(a0, qf[s], sa0);
      sa1 = MFMA16(a1, qf[s], sa1);
    }

    // ---- online softmax (fully wave-local; lane's q-row = l15) ----
    float sv[8];
    {
      const int qrow = q0 + w * 16 + l15;
      const bool needMask = CAUSAL && (k0 + 31 > q0 + w * 16);
#pragma unroll
      for (int kt2 = 0; kt2 < 2; ++kt2)
#pragma unroll
        for (int r = 0; r < 4; ++r) {
          float s = (kt2 == 0) ? sa0[r] : sa1[r];
          if (needMask) {
            int key = k0 + kt2 * 16 + quad * 4 + r;
            if (key > qrow) s = -1e30f;
          }
          sv[kt2 * 4 + r] = s;
        }
    }
    float tm = sv[0];
#pragma unroll
    for (int i = 1; i < 8; ++i) tm = fmaxf(tm, sv[i]);
    tm = fmaxf(tm, __shfl_xor(tm, 16));
    tm = fmaxf(tm, __shfl_xor(tm, 32));
    const float mn = fmaxf(m, tm);
    const float alpha = __expf(m - mn);
    m = mn;
    float pf[8];
    float ts = 0.f;
#pragma unroll
    for (int i = 0; i < 8; ++i) { pf[i] = __expf(sv[i] - mn); ts += pf[i]; }
    ts += __shfl_xor(ts, 16);
    ts += __shfl_xor(ts, 32);
    l = l * alpha + ts;
    if (__ballot(alpha < 0.99999f)) {
#pragma unroll
      for (int dt = 0; dt < 32; ++dt)
#pragma unroll
        for (int r = 0; r < 4; ++r) o[dt][r] *= alpha;
    }

    // ---- P^T (C-layout) -> B-operand frag via ds_bpermute, no LDS ----
    bf16x8 pb;
#pragma unroll
    for (int j = 0; j < 8; ++j) {
      const int r_ = j & 3;
      const int sl = (j < 4) ? laneA4 : laneB4;
      float v0 = __int_as_float(__builtin_amdgcn_ds_bpermute(sl, __float_as_int(pf[r_])));
      float v1 = __int_as_float(__builtin_amdgcn_ds_bpermute(sl, __float_as_int(pf[4 + r_])));
      pb[j] = (bf16)(quad < 2 ? v0 : v1);
    }

    // ---- O^T += V^T * P ----
#pragma unroll
    for (int dt = 0; dt < 32; ++dt) {
      bf16x8 a = *(const bf16x8*)&Vs[(dt * 16 + l15) * 32 + quad * 8];
      o[dt] = MFMA16(a, pb, o[dt]);
    }
  }

  // ---- epilogue: normalize, LDS transpose (reuse K/V buffers), coalesced store ----
  __syncthreads();
  const float inv = 1.f / l;
  bf16* Ow = lds_ + w * 8192;  // 16 KB per wave: [16 q][512 d]
#pragma unroll
  for (int dt = 0; dt < 32; ++dt) {
    bf16x4 v;
#pragma unroll
    for (int r = 0; r < 4; ++r) v[r] = (bf16)(o[dt][r] * inv);
    *(bf16x4*)&Ow[l15 * 512 + dt * 16 + quad * 4] = v;
  }
  bf16* Og = O + ((size_t)b * NS + q0 + w * 16) * ND;
#pragma unroll
  for (int it = 0; it < 16; ++it) {
    bf16x8 row = *(const bf16x8*)&Ow[it * 512 + lane * 8];
    *(bf16x8*)&Og[(size_t)it * ND + lane * 8] = row;
  }
}

// ---------------- NT GEMM: Out[M,N] = A[M,K] * W[N,K]^T (+bias)(+relu)(+res)(+LN stats) ----------------
template <int RES_MODE, bool HAS_BIAS, bool RELU, bool STATS>
__global__ __launch_bounds__(256) void k_gemm(const bf16* __restrict__ A, const bf16* __restrict__ W,
                                              const bf16* __restrict__ resid,
                                              const float* __restrict__ bias, bf16* __restrict__ Out,
                                              float* __restrict__ stats, int M, int N, int K,
                                              int rowOfs) {
  __shared__ bf16 As[128 * 64];
  __shared__ bf16 Ws[128 * 64];
  const int tid = threadIdx.x;
  const int w = tid >> 6, lane = tid & 63, quad = lane >> 4, l15 = lane & 15;
  const int m0 = blockIdx.x * 128, n0 = blockIdx.y * 128;
  const int wr = (w >> 1) * 64, wc = (w & 1) * 64;
  const int arow = lane >> 3, acol = (lane & 7) * 8;

  f32x4 acc[16];
#pragma unroll
  for (int i = 0; i < 16; ++i) acc[i] = (f32x4){0.f, 0.f, 0.f, 0.f};

  for (int k0 = 0; k0 < K; k0 += 64) {
    __syncthreads();
#pragma unroll
    for (int i = 0; i < 4; ++i) {
      const int rbase = (w * 4 + i) * 8 + arow;
      async_copy16(&As[(w * 4 + i) * 512], A + (size_t)(m0 + rbase) * K + k0 + acol);
      async_copy16(&Ws[(w * 4 + i) * 512], W + (size_t)(n0 + rbase) * K + k0 + acol);
    }
    __syncthreads();
#pragma unroll
    for (int s = 0; s < 2; ++s) {
      bf16x8 af[4], bw[4];
#pragma unroll
      for (int i = 0; i < 4; ++i) af[i] = *(const bf16x8*)&As[(wr + i * 16 + l15) * 64 + s * 32 + quad * 8];
#pragma unroll
      for (int j = 0; j < 4; ++j) bw[j] = *(const bf16x8*)&Ws[(wc + j * 16 + l15) * 64 + s * 32 + quad * 8];
#pragma unroll
      for (int i = 0; i < 4; ++i)
#pragma unroll
        for (int j = 0; j < 4; ++j) acc[i * 4 + j] = MFMA16(af[i], bw[j], acc[i * 4 + j]);
    }
  }

  float lsum = 0.f, lsq = 0.f;
#pragma unroll
  for (int i = 0; i < 4; ++i)
#pragma unroll
    for (int j = 0; j < 4; ++j)
#pragma unroll
      for (int r = 0; r < 4; ++r) {
        int row = m0 + wr + i * 16 + quad * 4 + r;
        int col = n0 + wc + j * 16 + l15;
        float v = acc[i * 4 + j][r];
        if (HAS_BIAS) v += bias[col];
        if (RELU) v = fmaxf(v, 0.f);
        if (RES_MODE == 2) v += (float)resid[(size_t)row * N + col];
        Out[(size_t)row * N + col] = (bf16)v;
        if (STATS) { lsum += v; lsq += v * v; }
      }

  if (STATS) {
    __syncthreads();
    float* red = (float*)As;
    red[tid] = lsum;
    red[256 + tid] = lsq;
    __syncthreads();
    for (int off = 128; off > 0; off >>= 1) {
      if (tid < off) { red[tid] += red[tid + off]; red[256 + tid] += red[256 + tid + off]; }
      __syncthreads();
    }
    if (tid == 0) {
      int bidx = (rowOfs + m0) >> 12;  // 4096 rows per batch
      atomicAdd(&stats[bidx * 2], red[0]);
      atomicAdd(&stats[bidx * 2 + 1], red[256]);
    }
  }
}

// ---------------- LayerNorm apply over (S,D) jointly per batch ----------------
template <bool FINAL>
__global__ void k_ln(const bf16* __restrict__ T, const float* __restrict__ stats,
                     const void* __restrict__ gp, const void* __restrict__ bp,
                     void* __restrict__ outp, const unsigned* __restrict__ flag) {
  const float invN = 1.f / 2097152.f;
  size_t i = ((size_t)(blockIdx.x * 256 + threadIdx.x)) * 8;
  int b = (int)(i >> 21);
  int sd = (int)(i & 2097151);
  float mu = stats[b * 2] * invN;
  float var = stats[b * 2 + 1] * invN - mu * mu;
  float rs = rsqrtf(var + 1e-5f);
  bool f32m = (*flag != 0);
  bf16x8 tv = *(const bf16x8*)(T + i);
  float gv[8], bv[8];
  if (f32m) {
    float4 a = *(const float4*)((const float*)gp + sd), c = *(const float4*)((const float*)gp + sd + 4);
    gv[0] = a.x; gv[1] = a.y; gv[2] = a.z; gv[3] = a.w; gv[4] = c.x; gv[5] = c.y; gv[6] = c.z; gv[7] = c.w;
    float4 e = *(const float4*)((const float*)bp + sd), f = *(const float4*)((const float*)bp + sd + 4);
    bv[0] = e.x; bv[1] = e.y; bv[2] = e.z; bv[3] = e.w; bv[4] = f.x; bv[5] = f.y; bv[6] = f.z; bv[7] = f.w;
  } else {
    bf16x8 g8 = *(const bf16x8*)((const bf16*)gp + sd);
    bf16x8 b8 = *(const bf16x8*)((const bf16*)bp + sd);
#pragma unroll
    for (int k = 0; k < 8; ++k) { gv[k] = (float)g8[k]; bv[k] = (float)b8[k]; }
  }
  float ov[8];
#pragma unroll
  for (int k = 0; k < 8; ++k) ov[k] = ((float)tv[k] - mu) * rs * gv[k] + bv[k];
  if (FINAL && f32m) {
    float4 o0 = {ov[0], ov[1], ov[2], ov[3]}, o1 = {ov[4], ov[5], ov[6], ov[7]};
    *(float4*)((float*)outp + i) = o0;
    *(float4*)((float*)outp + i + 4) = o1;
  } else {
    bf16x8 o8;
#pragma unroll
    for (int k = 0; k < 8; ++k) o8[k] = (bf16)ov[k];
    *(bf16x8*)((bf16*)outp + i) = o8;
  }
}

// ---------------- launch ----------------
extern "C" void kernel_launch(void* const* d_in, const int* in_sizes, int n_in, void* d_out,
                              int out_size, void* d_ws, size_t ws_size, hipStream_t stream) {
  (void)in_sizes; (void)n_in; (void)out_size;
  const void* x_raw = d_in[0];
  const void* enc_raw = d_in[1];
  const void* Wo1_raw = d_in[2];
  const void* Wo2_raw = d_in[3];
  const void* g1_raw = d_in[4];
  const void* bb1_raw = d_in[5];
  const void* g2_raw = d_in[6];
  const void* bb2_raw = d_in[7];
  const void* W1_raw = d_in[8];
  const void* bias1_raw = d_in[9];
  const void* W2_raw = d_in[10];
  const void* bias2_raw = d_in[11];

  char* w = (char*)d_ws;
  unsigned* flag = (unsigned*)(w + 0);
  float* stats = (float*)(w + 16);  // 3 stages x [B][2]
  float* b1f = (float*)(w + 1024);
  float* b2f = (float*)(w + 1024 + 8192);
  size_t off = 16384;
  const size_t nBSD = (size_t)NB * NS * ND;
  bf16* Wo1b = (bf16*)(w + off); off += (size_t)ND * ND * 2;
  bf16* Wo2b = (bf16*)(w + off); off += (size_t)ND * ND * 2;
  bf16* W1b = (bf16*)(w + off); off += (size_t)NF * ND * 2;
  bf16* W2b = (bf16*)(w + off); off += (size_t)ND * NF * 2;
  bf16* xb = (bf16*)(w + off); off += nBSD * 2;   // x bf16, later reused for enc
  bf16* Ab = (bf16*)(w + off); off += nBSD * 2;   // attention outputs
  bf16* Tb = (bf16*)(w + off); off += nBSD * 2;   // transposed-V scratch / pre-LN tensor
  bf16* X1b = (bf16*)(w + off); off += nBSD * 2;  // X1, later X2
  bf16* Hb = (bf16*)(w + off); off += (size_t)8192 * NF * 2;  // FFN hidden (half of M)
  if (ws_size < off) return;

  hipMemsetAsync(stats, 0, 24 * sizeof(float), stream);
  k_detect<<<1, 256, 0, stream>>>((const unsigned short*)x_raw, flag);

  k_norm_bf16<<<(int)(nBSD / 2048), 256, 0, stream>>>(x_raw, xb, flag, (int)nBSD);
  k_norm_bf16<<<(ND * ND) / 2048, 256, 0, stream>>>(Wo1_raw, Wo1b, flag, ND * ND);
  k_norm_bf16<<<(ND * ND) / 2048, 256, 0, stream>>>(Wo2_raw, Wo2b, flag, ND * ND);
  k_norm_bf16<<<(NF * ND) / 2048, 256, 0, stream>>>(W1_raw, W1b, flag, NF * ND);
  k_norm_bf16<<<(NF * ND) / 2048, 256, 0, stream>>>(W2_raw, W2b, flag, ND * NF);
  k_norm_f32<<<8, 256, 0, stream>>>(bias1_raw, b1f, flag, NF);
  k_norm_f32<<<2, 256, 0, stream>>>(bias2_raw, b2f, flag, ND);

  // 1) causal self-attention + Wo1 + residual(x) + LN1
  k_transpose<<<dim3(NS / 64, ND / 64, NB), 256, 0, stream>>>(xb, Tb);        // x^T as V
  k_attn2<true><<<dim3(NS / 64, NB), 256, 0, stream>>>(xb, xb, Tb, Ab);
  k_gemm<2, false, false, true><<<dim3(128, 4), 256, 0, stream>>>(Ab, Wo1b, xb, nullptr, Tb,
                                                                  stats + 0, NB * NS, ND, ND, 0);
  k_norm_bf16<<<(int)(nBSD / 2048), 256, 0, stream>>>(enc_raw, xb, flag, (int)nBSD);  // xb := enc
  k_ln<false><<<(int)(nBSD / 2048), 256, 0, stream>>>(Tb, stats + 0, g1_raw, bb1_raw, X1b, flag);

  // 2) cross attention (q=k=enc, v=X1) + Wo2 + residual(X1) + LN2
  k_transpose<<<dim3(NS / 64, ND / 64, NB), 256, 0, stream>>>(X1b, Tb);       // X1^T as V
  k_attn2<false><<<dim3(NS / 64, NB), 256, 0, stream>>>(xb, xb, Tb, Ab);
  k_gemm<2, false, false, true><<<dim3(128, 4), 256, 0, stream>>>(Ab, Wo2b, X1b, nullptr, Tb,
                                                                  stats + 8, NB * NS, ND, ND, 0);
  k_ln<false><<<(int)(nBSD / 2048), 256, 0, stream>>>(Tb, stats + 8, g2_raw, bb2_raw, X1b, flag);
  // X1b now holds X2

  // 3) FFN + residual(X2) + LN (ln2 params), in two 8192-row chunks
  for (int c = 0; c < 2; ++c) {
    size_t ro = (size_t)c * 8192;
    k_gemm<0, true, true, false><<<dim3(64, 16), 256, 0, stream>>>(X1b + ro * ND, W1b, nullptr, b1f,
                                                                   Hb, nullptr, 8192, NF, ND, 0);
    k_gemm<2, true, false, true><<<dim3(64, 4), 256, 0, stream>>>(Hb, W2b, X1b + ro * ND, b2f,
                                                                  Tb + ro * ND, stats + 16, 8192,
                                                                  ND, NF, (int)ro);
  }
  k_ln<true><<<(int)(nBSD / 2048), 256, 0, stream>>>(Tb, stats + 16, g2_raw, bb2_raw, d_out, flag);
}

// Round 3
// 988.737 us; speedup vs baseline: 2.8273x; 1.1142x over previous
//
// TransformerDecoderBlock on MI355X (gfx950) — round 3: flash-attn + 2-way K-split (flash-decoding).
// Attention: BQ=64 (4 waves x 16 q-rows), BK=32 full-D tiles, Q in registers, S^T=K*Q^T wave-local
// softmax, in-register P^T->B via ds_bpermute, O^T accumulators. NEW: grid z=2 splits the key range
// per q-block -> 512 blocks (2 blocks/CU) so staging drain + softmax bubbles overlap across blocks;
// partial (O/l, m, l) merged by k_merge. Partials live in the (then-unused) FFN Hb scratch.
// GEMM/LN pipeline unchanged. Requires ws_size >= ~101 MB (guarded).
#include <hip/hip_runtime.h>
#include <cstdint>
#include <cstddef>

#define NB 4
#define NS 4096
#define ND 512
#define NF 2048

typedef __bf16 bf16;
typedef __attribute__((ext_vector_type(8))) __bf16 bf16x8;
typedef __attribute__((ext_vector_type(4))) __bf16 bf16x4;
typedef __attribute__((ext_vector_type(4))) float f32x4;

#define MFMA16(a, b, c) __builtin_amdgcn_mfma_f32_16x16x32_bf16((a), (b), (c), 0, 0, 0)

// Async global->LDS, 16B per lane. LDS dest is wave-uniform base; lane i lands at base+16*i.
__device__ __forceinline__ void async_copy16(void* lds, const void* g) {
  __builtin_amdgcn_global_load_lds(
      (__attribute__((address_space(1))) unsigned int*)(uintptr_t)g,
      (__attribute__((address_space(3))) unsigned int*)(unsigned)(uintptr_t)lds,
      16, 0, 0);
}

// ---------------- dtype detect ----------------
__global__ void k_detect(const unsigned short* __restrict__ x, unsigned* __restrict__ flag) {
  __shared__ int cnt;
  if (threadIdx.x == 0) cnt = 0;
  __syncthreads();
  int bad = 0;
  for (int i = threadIdx.x; i < 2048; i += 256) {
    unsigned e = (x[i] >> 7) & 0xFF;
    if (e < 100 || e > 140) bad++;
  }
  atomicAdd(&cnt, bad);
  __syncthreads();
  if (threadIdx.x == 0) *flag = (cnt > 200) ? 1u : 0u;  // 1 => inputs are f32
}

// ---------------- input normalization ----------------
__global__ void k_norm_bf16(const void* __restrict__ src, bf16* __restrict__ dst,
                            const unsigned* __restrict__ flag, int n) {
  int i = (blockIdx.x * 256 + threadIdx.x) * 8;
  if (i >= n) return;
  if (*flag) {
    const float* s = (const float*)src;
    float4 a = *(const float4*)(s + i);
    float4 c = *(const float4*)(s + i + 4);
    bf16x8 v;
    v[0] = (bf16)a.x; v[1] = (bf16)a.y; v[2] = (bf16)a.z; v[3] = (bf16)a.w;
    v[4] = (bf16)c.x; v[5] = (bf16)c.y; v[6] = (bf16)c.z; v[7] = (bf16)c.w;
    *(bf16x8*)(dst + i) = v;
  } else {
    *(uint4*)(dst + i) = *(const uint4*)((const bf16*)src + i);
  }
}

__global__ void k_norm_f32(const void* __restrict__ src, float* __restrict__ dst,
                           const unsigned* __restrict__ flag, int n) {
  int i = blockIdx.x * 256 + threadIdx.x;
  if (i >= n) return;
  dst[i] = (*flag) ? ((const float*)src)[i] : (float)((const bf16*)src)[i];
}

// ---------------- transpose [B][S][D] -> [B][D][S] (bf16) ----------------
__global__ void k_transpose(const bf16* __restrict__ in, bf16* __restrict__ out) {
  __shared__ bf16 t[64][72];
  const int b = blockIdx.z, s0 = blockIdx.x * 64, d0 = blockIdx.y * 64;
  const int tid = threadIdx.x;
#pragma unroll
  for (int it = 0; it < 2; ++it) {
    int slot = it * 256 + tid;
    int r = slot >> 3, c = (slot & 7) * 8;
    *(bf16x8*)&t[r][c] = *(const bf16x8*)&in[((size_t)b * NS + s0 + r) * ND + d0 + c];
  }
  __syncthreads();
#pragma unroll
  for (int it = 0; it < 2; ++it) {
    int slot = it * 256 + tid;
    int r = slot >> 3, c = (slot & 7) * 8;  // r = local dim, c = local seq base
    bf16x8 v;
#pragma unroll
    for (int k = 0; k < 8; ++k) v[k] = t[c + k][r];
    *(bf16x8*)&out[((size_t)b * ND + d0 + r) * NS + s0 + c] = v;
  }
}

// ---------------- flash attention with 2-way K-split ----------------
// Q,K: [B][S][D] bf16. Vt: [B][D][S] bf16 (pre-transposed). O0/O1: [B][S][D] bf16 partials (O/l).
// ml: float2 per (z,b,row): (m, l). Grid: (NS/64, NB, 2).
template <bool CAUSAL>
__global__ __launch_bounds__(256, 2) void k_attn3(const bf16* __restrict__ Q,
                                                  const bf16* __restrict__ Km,
                                                  const bf16* __restrict__ Vt,
                                                  bf16* __restrict__ O0, bf16* __restrict__ O1,
                                                  float2* __restrict__ ml) {
  __shared__ bf16 lds_[32768];  // 64 KB: Ks [32 x 512], Vs [512 x 32]
  bf16* Ks = lds_;
  bf16* Vs = lds_ + 16384;

  const int tid = threadIdx.x;
  const int w = tid >> 6, lane = tid & 63, quad = lane >> 4, l15 = lane & 15;
  const int b = blockIdx.y;
  const int q0 = blockIdx.x * 64;
  const int z = blockIdx.z;

  const bf16* Kg = Km + (size_t)b * NS * ND;
  const bf16* Vg = Vt + (size_t)b * ND * NS;

  // ---- Q fragments in registers, pre-scaled by 1/sqrt(D) ----
  const bf16* Qg = Q + ((size_t)b * NS + q0 + w * 16 + l15) * ND;
  bf16x8 qf[16];
#pragma unroll
  for (int s = 0; s < 16; ++s) qf[s] = *(const bf16x8*)&Qg[s * 32 + quad * 8];
#pragma unroll
  for (int s = 0; s < 16; ++s)
#pragma unroll
    for (int j = 0; j < 8; ++j) qf[s][j] = (bf16)((float)qf[s][j] * 0.044194173824159216f);

  f32x4 o[32];  // O^T: o[dt] -> (d = dt*16 + quad*4 + r, q = l15)
#pragma unroll
  for (int i = 0; i < 32; ++i) o[i] = (f32x4){0.f, 0.f, 0.f, 0.f};

  float m = -1e30f, l = 0.f;  // per-lane, q = l15 (replicated across quads)

  const int T = CAUSAL ? (q0 / 32 + 2) : (NS / 32);
  const int tA = (T + 1) >> 1;
  const int kt0 = z ? tA : 0;
  const int kt1 = z ? T : tA;
  const int laneA4 = ((((quad * 2) & 3) * 16) + l15) * 4;
  const int laneB4 = ((((quad * 2 + 1) & 3) * 16) + l15) * 4;

  for (int kt = kt0; kt < kt1; ++kt) {
    const int k0 = kt * 32;
    __syncthreads();  // previous tile's LDS reads complete

    // ---- stage K tile [32][512] with per-row XOR-swizzle on 16B chunks ----
#pragma unroll
    for (int i = 0; i < 8; ++i) {
      const int r = w * 8 + i;
      const int g = (lane & ~7) | ((lane ^ r) & 7);
      async_copy16(&Ks[r * 512], Kg + (size_t)(k0 + r) * ND + g * 8);
    }
    // ---- stage V^T tile [512][32] ----
#pragma unroll
    for (int i = 0; i < 8; ++i) {
      const int d0 = (w * 8 + i) * 16;
      async_copy16(&Vs[d0 * 32], Vg + (size_t)(d0 + (lane >> 2)) * NS + k0 + (lane & 3) * 8);
    }
    __syncthreads();  // staging drained

    // ---- S^T = K * Q^T ----
    f32x4 sa0 = (f32x4){0.f, 0.f, 0.f, 0.f};
    f32x4 sa1 = (f32x4){0.f, 0.f, 0.f, 0.f};
#pragma unroll
    for (int s = 0; s < 16; ++s) {
      const int lc = s * 4 + quad;
      const int swz = ((lc & ~7) | ((lc ^ l15) & 7)) * 8;
      bf16x8 a0 = *(const bf16x8*)&Ks[l15 * 512 + swz];
      bf16x8 a1 = *(const bf16x8*)&Ks[(16 + l15) * 512 + swz];
      sa0 = MFMA16(a0, qf[s], sa0);
      sa1 = MFMA16(a1, qf[s], sa1);
    }

    // ---- online softmax (fully wave-local; lane's q-row = l15) ----
    float sv[8];
    {
      const int qrow = q0 + w * 16 + l15;
      const bool needMask = CAUSAL && (k0 + 31 > q0 + w * 16);
#pragma unroll
      for (int kt2 = 0; kt2 < 2; ++kt2)
#pragma unroll
        for (int r = 0; r < 4; ++r) {
          float s = (kt2 == 0) ? sa0[r] : sa1[r];
          if (needMask) {
            int key = k0 + kt2 * 16 + quad * 4 + r;
            if (key > qrow) s = -1e30f;
          }
          sv[kt2 * 4 + r] = s;
        }
    }
    float tm = sv[0];
#pragma unroll
    for (int i = 1; i < 8; ++i) tm = fmaxf(tm, sv[i]);
    tm = fmaxf(tm, __shfl_xor(tm, 16));
    tm = fmaxf(tm, __shfl_xor(tm, 32));
    const float mn = fmaxf(m, tm);
    const float alpha = __expf(m - mn);
    m = mn;
    float pf[8];
    float ts = 0.f;
#pragma unroll
    for (int i = 0; i < 8; ++i) { pf[i] = __expf(sv[i] - mn); ts += pf[i]; }
    ts += __shfl_xor(ts, 16);
    ts += __shfl_xor(ts, 32);
    l = l * alpha + ts;
    if (__ballot(alpha < 0.99999f)) {
#pragma unroll
      for (int dt = 0; dt < 32; ++dt)
#pragma unroll
        for (int r = 0; r < 4; ++r) o[dt][r] *= alpha;
    }

    // ---- P^T (C-layout) -> B-operand frag via ds_bpermute, no LDS ----
    bf16x8 pb;
#pragma unroll
    for (int j = 0; j < 8; ++j) {
      const int r_ = j & 3;
      const int sl = (j < 4) ? laneA4 : laneB4;
      float v0 = __int_as_float(__builtin_amdgcn_ds_bpermute(sl, __float_as_int(pf[r_])));
      float v1 = __int_as_float(__builtin_amdgcn_ds_bpermute(sl, __float_as_int(pf[4 + r_])));
      pb[j] = (bf16)(quad < 2 ? v0 : v1);
    }

    // ---- O^T += V^T * P ----
#pragma unroll
    for (int dt = 0; dt < 32; ++dt) {
      bf16x8 a = *(const bf16x8*)&Vs[(dt * 16 + l15) * 32 + quad * 8];
      o[dt] = MFMA16(a, pb, o[dt]);
    }
  }

  // ---- epilogue: normalize by 1/l, write partial + (m,l) ----
  __syncthreads();
  const float inv = 1.f / l;
  if (lane < 16 && quad == 0) ml[((size_t)z * NB + b) * NS + q0 + w * 16 + lane] = make_float2(m, l);
  bf16* Ow = lds_ + w * 8192;  // 16 KB per wave: [16 q][512 d]
#pragma unroll
  for (int dt = 0; dt < 32; ++dt) {
    bf16x4 v;
#pragma unroll
    for (int r = 0; r < 4; ++r) v[r] = (bf16)(o[dt][r] * inv);
    *(bf16x4*)&Ow[l15 * 512 + dt * 16 + quad * 4] = v;
  }
  bf16* Og = (z ? O1 : O0) + ((size_t)b * NS + q0 + w * 16) * ND;
#pragma unroll
  for (int it = 0; it < 16; ++it) {
    bf16x8 row = *(const bf16x8*)&Ow[it * 512 + lane * 8];
    *(bf16x8*)&Og[(size_t)it * ND + lane * 8] = row;
  }
}

// ---------------- merge two K-split partials: O0 = c0*O0 + c1*O1 ----------------
__global__ void k_merge(bf16* __restrict__ O0, const bf16* __restrict__ O1,
                        const float2* __restrict__ ml) {
  size_t i = ((size_t)blockIdx.x * 256 + threadIdx.x) * 8;
  int row = (int)(i >> 9);  // / 512
  float2 a = ml[row];
  float2 c = ml[(size_t)NB * NS + row];
  float M = fmaxf(a.x, c.x);
  float w0 = __expf(a.x - M) * a.y;
  float w1 = __expf(c.x - M) * c.y;
  float den = 1.f / (w0 + w1);
  float c0 = w0 * den, c1 = w1 * den;
  bf16x8 v0 = *(const bf16x8*)(O0 + i);
  bf16x8 v1 = *(const bf16x8*)(O1 + i);
  bf16x8 ov;
#pragma unroll
  for (int k = 0; k < 8; ++k) ov[k] = (bf16)(c0 * (float)v0[k] + c1 * (float)v1[k]);
  *(bf16x8*)(O0 + i) = ov;
}

// ---------------- NT GEMM: Out[M,N] = A[M,K] * W[N,K]^T (+bias)(+relu)(+res)(+LN stats) ----------------
template <int RES_MODE, bool HAS_BIAS, bool RELU, bool STATS>
__global__ __launch_bounds__(256) void k_gemm(const bf16* __restrict__ A, const bf16* __restrict__ W,
                                              const bf16* __restrict__ resid,
                                              const float* __restrict__ bias, bf16* __restrict__ Out,
                                              float* __restrict__ stats, int M, int N, int K,
                                              int rowOfs) {
  __shared__ bf16 As[128 * 64];
  __shared__ bf16 Ws[128 * 64];
  const int tid = threadIdx.x;
  const int w = tid >> 6, lane = tid & 63, quad = lane >> 4, l15 = lane & 15;
  const int m0 = blockIdx.x * 128, n0 = blockIdx.y * 128;
  const int wr = (w >> 1) * 64, wc = (w & 1) * 64;
  const int arow = lane >> 3, acol = (lane & 7) * 8;

  f32x4 acc[16];
#pragma unroll
  for (int i = 0; i < 16; ++i) acc[i] = (f32x4){0.f, 0.f, 0.f, 0.f};

  for (int k0 = 0; k0 < K; k0 += 64) {
    __syncthreads();
#pragma unroll
    for (int i = 0; i < 4; ++i) {
      const int rbase = (w * 4 + i) * 8 + arow;
      async_copy16(&As[(w * 4 + i) * 512], A + (size_t)(m0 + rbase) * K + k0 + acol);
      async_copy16(&Ws[(w * 4 + i) * 512], W + (size_t)(n0 + rbase) * K + k0 + acol);
    }
    __syncthreads();
#pragma unroll
    for (int s = 0; s < 2; ++s) {
      bf16x8 af[4], bw[4];
#pragma unroll
      for (int i = 0; i < 4; ++i) af[i] = *(const bf16x8*)&As[(wr + i * 16 + l15) * 64 + s * 32 + quad * 8];
#pragma unroll
      for (int j = 0; j < 4; ++j) bw[j] = *(const bf16x8*)&Ws[(wc + j * 16 + l15) * 64 + s * 32 + quad * 8];
#pragma unroll
      for (int i = 0; i < 4; ++i)
#pragma unroll
        for (int j = 0; j < 4; ++j) acc[i * 4 + j] = MFMA16(af[i], bw[j], acc[i * 4 + j]);
    }
  }

  float lsum = 0.f, lsq = 0.f;
#pragma unroll
  for (int i = 0; i < 4; ++i)
#pragma unroll
    for (int j = 0; j < 4; ++j)
#pragma unroll
      for (int r = 0; r < 4; ++r) {
        int row = m0 + wr + i * 16 + quad * 4 + r;
        int col = n0 + wc + j * 16 + l15;
        float v = acc[i * 4 + j][r];
        if (HAS_BIAS) v += bias[col];
        if (RELU) v = fmaxf(v, 0.f);
        if (RES_MODE == 2) v += (float)resid[(size_t)row * N + col];
        Out[(size_t)row * N + col] = (bf16)v;
        if (STATS) { lsum += v; lsq += v * v; }
      }

  if (STATS) {
    __syncthreads();
    float* red = (float*)As;
    red[tid] = lsum;
    red[256 + tid] = lsq;
    __syncthreads();
    for (int off = 128; off > 0; off >>= 1) {
      if (tid < off) { red[tid] += red[tid + off]; red[256 + tid] += red[256 + tid + off]; }
      __syncthreads();
    }
    if (tid == 0) {
      int bidx = (rowOfs + m0) >> 12;  // 4096 rows per batch
      atomicAdd(&stats[bidx * 2], red[0]);
      atomicAdd(&stats[bidx * 2 + 1], red[256]);
    }
  }
}

// ---------------- LayerNorm apply over (S,D) jointly per batch ----------------
template <bool FINAL>
__global__ void k_ln(const bf16* __restrict__ T, const float* __restrict__ stats,
                     const void* __restrict__ gp, const void* __restrict__ bp,
                     void* __restrict__ outp, const unsigned* __restrict__ flag) {
  const float invN = 1.f / 2097152.f;
  size_t i = ((size_t)(blockIdx.x * 256 + threadIdx.x)) * 8;
  int b = (int)(i >> 21);
  int sd = (int)(i & 2097151);
  float mu = stats[b * 2] * invN;
  float var = stats[b * 2 + 1] * invN - mu * mu;
  float rs = rsqrtf(var + 1e-5f);
  bool f32m = (*flag != 0);
  bf16x8 tv = *(const bf16x8*)(T + i);
  float gv[8], bv[8];
  if (f32m) {
    float4 a = *(const float4*)((const float*)gp + sd), c = *(const float4*)((const float*)gp + sd + 4);
    gv[0] = a.x; gv[1] = a.y; gv[2] = a.z; gv[3] = a.w; gv[4] = c.x; gv[5] = c.y; gv[6] = c.z; gv[7] = c.w;
    float4 e = *(const float4*)((const float*)bp + sd), f = *(const float4*)((const float*)bp + sd + 4);
    bv[0] = e.x; bv[1] = e.y; bv[2] = e.z; bv[3] = e.w; bv[4] = f.x; bv[5] = f.y; bv[6] = f.z; bv[7] = f.w;
  } else {
    bf16x8 g8 = *(const bf16x8*)((const bf16*)gp + sd);
    bf16x8 b8 = *(const bf16x8*)((const bf16*)bp + sd);
#pragma unroll
    for (int k = 0; k < 8; ++k) { gv[k] = (float)g8[k]; bv[k] = (float)b8[k]; }
  }
  float ov[8];
#pragma unroll
  for (int k = 0; k < 8; ++k) ov[k] = ((float)tv[k] - mu) * rs * gv[k] + bv[k];
  if (FINAL && f32m) {
    float4 o0 = {ov[0], ov[1], ov[2], ov[3]}, o1 = {ov[4], ov[5], ov[6], ov[7]};
    *(float4*)((float*)outp + i) = o0;
    *(float4*)((float*)outp + i + 4) = o1;
  } else {
    bf16x8 o8;
#pragma unroll
    for (int k = 0; k < 8; ++k) o8[k] = (bf16)ov[k];
    *(bf16x8*)((bf16*)outp + i) = o8;
  }
}

// ---------------- launch ----------------
extern "C" void kernel_launch(void* const* d_in, const int* in_sizes, int n_in, void* d_out,
                              int out_size, void* d_ws, size_t ws_size, hipStream_t stream) {
  (void)in_sizes; (void)n_in; (void)out_size;
  const void* x_raw = d_in[0];
  const void* enc_raw = d_in[1];
  const void* Wo1_raw = d_in[2];
  const void* Wo2_raw = d_in[3];
  const void* g1_raw = d_in[4];
  const void* bb1_raw = d_in[5];
  const void* g2_raw = d_in[6];
  const void* bb2_raw = d_in[7];
  const void* W1_raw = d_in[8];
  const void* bias1_raw = d_in[9];
  const void* W2_raw = d_in[10];
  const void* bias2_raw = d_in[11];

  char* w = (char*)d_ws;
  unsigned* flag = (unsigned*)(w + 0);
  float* stats = (float*)(w + 16);  // 3 stages x [B][2]
  float* b1f = (float*)(w + 1024);
  float* b2f = (float*)(w + 1024 + 8192);
  size_t off = 16384;
  const size_t nBSD = (size_t)NB * NS * ND;
  bf16* Wo1b = (bf16*)(w + off); off += (size_t)ND * ND * 2;
  bf16* Wo2b = (bf16*)(w + off); off += (size_t)ND * ND * 2;
  bf16* W1b = (bf16*)(w + off); off += (size_t)NF * ND * 2;
  bf16* W2b = (bf16*)(w + off); off += (size_t)ND * NF * 2;
  bf16* xb = (bf16*)(w + off); off += nBSD * 2;   // x bf16, later reused for enc
  bf16* Ab = (bf16*)(w + off); off += nBSD * 2;   // attention output (partial 0, then merged)
  bf16* Tb = (bf16*)(w + off); off += nBSD * 2;   // transposed-V scratch / pre-LN tensor
  bf16* X1b = (bf16*)(w + off); off += nBSD * 2;  // X1, later X2
  bf16* Hb = (bf16*)(w + off); off += (size_t)8192 * NF * 2;  // FFN hidden; attn partial 1 + ml before FFN
  if (ws_size < off) return;

  bf16* O1b = Hb;  // 16 MB partial-1 region (Hb is dead until FFN phase)
  float2* mlb = (float2*)((char*)Hb + nBSD * 2);  // 2*B*S float2 = 256 KB

  hipMemsetAsync(stats, 0, 24 * sizeof(float), stream);
  k_detect<<<1, 256, 0, stream>>>((const unsigned short*)x_raw, flag);

  k_norm_bf16<<<(int)(nBSD / 2048), 256, 0, stream>>>(x_raw, xb, flag, (int)nBSD);
  k_norm_bf16<<<(ND * ND) / 2048, 256, 0, stream>>>(Wo1_raw, Wo1b, flag, ND * ND);
  k_norm_bf16<<<(ND * ND) / 2048, 256, 0, stream>>>(Wo2_raw, Wo2b, flag, ND * ND);
  k_norm_bf16<<<(NF * ND) / 2048, 256, 0, stream>>>(W1_raw, W1b, flag, NF * ND);
  k_norm_bf16<<<(NF * ND) / 2048, 256, 0, stream>>>(W2_raw, W2b, flag, ND * NF);
  k_norm_f32<<<8, 256, 0, stream>>>(bias1_raw, b1f, flag, NF);
  k_norm_f32<<<2, 256, 0, stream>>>(bias2_raw, b2f, flag, ND);

  // 1) causal self-attention + Wo1 + residual(x) + LN1
  k_transpose<<<dim3(NS / 64, ND / 64, NB), 256, 0, stream>>>(xb, Tb);        // x^T as V
  k_attn3<true><<<dim3(NS / 64, NB, 2), 256, 0, stream>>>(xb, xb, Tb, Ab, O1b, mlb);
  k_merge<<<(int)(nBSD / 2048), 256, 0, stream>>>(Ab, O1b, mlb);
  k_gemm<2, false, false, true><<<dim3(128, 4), 256, 0, stream>>>(Ab, Wo1b, xb, nullptr, Tb,
                                                                  stats + 0, NB * NS, ND, ND, 0);
  k_norm_bf16<<<(int)(nBSD / 2048), 256, 0, stream>>>(enc_raw, xb, flag, (int)nBSD);  // xb := enc
  k_ln<false><<<(int)(nBSD / 2048), 256, 0, stream>>>(Tb, stats + 0, g1_raw, bb1_raw, X1b, flag);

  // 2) cross attention (q=k=enc, v=X1) + Wo2 + residual(X1) + LN2
  k_transpose<<<dim3(NS / 64, ND / 64, NB), 256, 0, stream>>>(X1b, Tb);       // X1^T as V
  k_attn3<false><<<dim3(NS / 64, NB, 2), 256, 0, stream>>>(xb, xb, Tb, Ab, O1b, mlb);
  k_merge<<<(int)(nBSD / 2048), 256, 0, stream>>>(Ab, O1b, mlb);
  k_gemm<2, false, false, true><<<dim3(128, 4), 256, 0, stream>>>(Ab, Wo2b, X1b, nullptr, Tb,
                                                                  stats + 8, NB * NS, ND, ND, 0);
  k_ln<false><<<(int)(nBSD / 2048), 256, 0, stream>>>(Tb, stats + 8, g2_raw, bb2_raw, X1b, flag);
  // X1b now holds X2

  // 3) FFN + residual(X2) + LN (ln2 params), in two 8192-row chunks
  for (int c = 0; c < 2; ++c) {
    size_t ro = (size_t)c * 8192;
    k_gemm<0, true, true, false><<<dim3(64, 16), 256, 0, stream>>>(X1b + ro * ND, W1b, nullptr, b1f,
                                                                   Hb, nullptr, 8192, NF, ND, 0);
    k_gemm<2, true, false, true><<<dim3(64, 4), 256, 0, stream>>>(Hb, W2b, X1b + ro * ND, b2f,
                                                                  Tb + ro * ND, stats + 16, 8192,
                                                                  ND, NF, (int)ro);
  }
  k_ln<true><<<(int)(nBSD / 2048), 256, 0, stream>>>(Tb, stats + 16, g2_raw, bb2_raw, d_out, flag);
}